// Round 1
// baseline (6808.138 us; speedup 1.0000x reference)
//
#include <hip/hip_runtime.h>

#define TT 512
#define VV 64

typedef _Float16 f16;
typedef f16 f16x8 __attribute__((ext_vector_type(8)));
typedef f16 f16x4 __attribute__((ext_vector_type(4)));
typedef float f32x4v __attribute__((ext_vector_type(4)));

#define MFMA(A_,B_,C_) __builtin_amdgcn_mfma_f32_16x16x32_f16((A_),(B_),(C_),0,0,0)
#define AT_LD(p)   __hip_atomic_load((p), __ATOMIC_RELAXED, __HIP_MEMORY_SCOPE_AGENT)
#define AT_ST(p,v) __hip_atomic_store((p),(v), __ATOMIC_RELAXED, __HIP_MEMORY_SCOPE_AGENT)

__device__ __forceinline__ void barrier_lds(){ asm volatile("s_waitcnt lgkmcnt(0)\n\ts_barrier" ::: "memory"); }
__device__ __forceinline__ void wait_vm0(){ asm volatile("s_waitcnt vmcnt(0)" ::: "memory"); }

__device__ __forceinline__ float4 ld4(const float* p){ return *(const float4*)p; }

__device__ __forceinline__ f16x8 ldA8(const float* p){
  f16x8 a;
  #pragma unroll
  for (int j = 0; j < 8; ++j) a[j] = (f16)p[j];
  return a;
}

// write 4 consecutive-k f16 values (k=d0..d0+3, col=b) into a B-fragment buffer
// layout: [kt][lane'][j] with lane' = ((d&31)>>3)*16 + b, j = d&7
__device__ __forceinline__ void fragW(f16x8* buf, int d0, int b, const float* h4){
  const int kt = d0 >> 5, qq = (d0 >> 3) & 3, j0 = d0 & 7;
  f16x4 v;
  #pragma unroll
  for (int e = 0; e < 4; ++e) v[e] = (f16)h4[e];
  f16* base = (f16*)(buf + (kt*64 + qq*16 + b));
  *(f16x4*)(base + j0) = v;
}

__device__ __forceinline__ void publish4(float* slot, int idx0, const float* h4){
  #pragma unroll
  for (int e = 0; e < 4; ++e) AT_ST(slot + idx0 + e, h4[e]);
}

__device__ __forceinline__ void import4(const float* slot, int idx0, float* h4){
  #pragma unroll
  for (int e = 0; e < 4; ++e) h4[e] = AT_LD(slot + idx0 + e);
}

__device__ __forceinline__ void spin_on(unsigned* f, unsigned val){
  if ((threadIdx.x & 63) == 0){
    unsigned g = 0;
    while (AT_LD(f) != val && ++g < (1u << 20)) {}
  }
  asm volatile("" ::: "memory");
}

__device__ __forceinline__ void gates_upd(const f32x4v* Ci, const f32x4v* Ch,
                                          const float* bR, const float* bZ,
                                          const float* bI, const float* bH,
                                          float* hp){
  #pragma unroll
  for (int e = 0; e < 4; ++e){
    float rr = 1.f/(1.f + __expf(-(Ci[0][e] + Ch[0][e] + bR[e])));
    float zz = 1.f/(1.f + __expf(-(Ci[1][e] + Ch[1][e] + bZ[e])));
    float nv = Ci[2][e] + bI[e] + rr*(Ch[2][e] + bH[e]);
    float nn = 1.f - 2.f/(1.f + __expf(2.f*nv));
    hp[e] = (1.f - zz)*nn + zz*hp[e];
  }
}

__launch_bounds__(256, 1)
__global__ void k_grud(const float* __restrict__ x,   const float* __restrict__ dd,
                       const float* __restrict__ m1,
                       const float* __restrict__ h01, const float* __restrict__ h02,
                       const float* __restrict__ h03,
                       const float* __restrict__ Wih1, const float* __restrict__ Whh1,
                       const float* __restrict__ bih1, const float* __restrict__ bhh1,
                       const float* __restrict__ Wih2, const float* __restrict__ Whh2,
                       const float* __restrict__ bih2, const float* __restrict__ bhh2,
                       const float* __restrict__ Wih3, const float* __restrict__ Whh3,
                       const float* __restrict__ bih3, const float* __restrict__ bhh3,
                       const float* __restrict__ Wout, const float* __restrict__ bout,
                       const float* __restrict__ Wdx,  const float* __restrict__ bdx,
                       const float* __restrict__ Wdh,  const float* __restrict__ bdh,
                       float* __restrict__ y, float* __restrict__ wsd, unsigned* __restrict__ wsf)
{
  __shared__ f16x8 sX1[2][128];      // x1 B-frags, [par][kt*64+lane]
  __shared__ f16x8 sHP[2][3][256];   // decayed h_prev frags, [par][layer]
  __shared__ f16x8 sH3F[2][256];     // undecayed h3 (head input)
  __shared__ f16x8 sH1F[256];        // fresh h1 (same-step)
  __shared__ f16x8 sH2F[256];        // fresh h2
  __shared__ float sBRZ[3][256];     // b_ih+b_hh for r(0..127), z(128..255)
  __shared__ float sBN[3][2][128];   // n-gate: b_ih, b_hh separately

  const int tid = threadIdx.x;
  const int w = tid >> 6, lane = tid & 63;
  const int q = lane >> 4, r = lane & 15;
  const int blk = blockIdx.x;
  const int pair = blk & 31, half = blk >> 5;
  const int b0 = pair << 4;
  const int dOwn0 = half*64 + w*16 + 4*q;         // this lane's own d-base (+e)
  const int dImp0 = (64 - half*64) + w*16 + 4*q;  // partner-half d-base
  const int bx = w*4 + q, v0 = 4*r;               // x-loader role

  // biases -> LDS
  {
    const int i = tid; // 0..255
    sBRZ[0][i] = bih1[i] + bhh1[i];
    sBRZ[1][i] = bih2[i] + bhh2[i];
    sBRZ[2][i] = bih3[i] + bhh3[i];
    if (i < 128){
      sBN[0][0][i] = bih1[256+i]; sBN[0][1][i] = bhh1[256+i];
      sBN[1][0][i] = bih2[256+i]; sBN[1][1][i] = bhh2[256+i];
      sBN[2][0][i] = bih3[256+i]; sBN[2][1][i] = bhh3[256+i];
    }
  }

  // ---- register-resident weight A-fragments (this block's M-half, wave's triple) ----
  f16x8 Ai1[3][2], Ah1[3][4], Ai2[3][4], Ah2[3][4], Ai3[3][4], Ah3[3][4];
  #pragma unroll
  for (int g = 0; g < 3; ++g){
    const int mrow = (g*8 + half*4 + w)*16 + r;
    #pragma unroll
    for (int kt = 0; kt < 2; ++kt)
      Ai1[g][kt] = ldA8(Wih1 + mrow*64 + kt*32 + q*8);
    #pragma unroll
    for (int kt = 0; kt < 4; ++kt){
      const int ko = kt*32 + q*8;
      Ah1[g][kt] = ldA8(Whh1 + mrow*128 + ko);
      Ai2[g][kt] = ldA8(Wih2 + mrow*128 + ko);
      Ah2[g][kt] = ldA8(Whh2 + mrow*128 + ko);
      Ai3[g][kt] = ldA8(Wih3 + mrow*128 + ko);
      Ah3[g][kt] = ldA8(Whh3 + mrow*128 + ko);
    }
  }
  // head weights (rows 0..3 valid, rest zero)
  f16x8 aO[4]; float bo4[4];
  #pragma unroll
  for (int kt = 0; kt < 4; ++kt){
    f16x8 a;
    #pragma unroll
    for (int j = 0; j < 8; ++j)
      a[j] = (r < 4) ? (f16)Wout[r*128 + kt*32 + q*8 + j] : (f16)0.f;
    aO[kt] = a;
  }
  #pragma unroll
  for (int e = 0; e < 4; ++e) bo4[e] = bout[e];

  // decay params (per-lane fixed positions)
  float WdhO[4], bdhO[4], WdhI[4], bdhI[4], Wdx4[4], bdx4[4];
  #pragma unroll
  for (int e = 0; e < 4; ++e){
    WdhO[e] = Wdh[dOwn0+e]; bdhO[e] = bdh[dOwn0+e];
    WdhI[e] = Wdh[dImp0+e]; bdhI[e] = bdh[dImp0+e];
    Wdx4[e] = Wdx[v0+e];    bdx4[e] = bdx[v0+e];
  }

  // h0 (both halves from inputs; no exchange needed at t=0)
  float hO[3][4], hI[3][4];
  {
    const float* hs[3] = {h01, h02, h03};
    #pragma unroll
    for (int L = 0; L < 3; ++L){
      float4 a = ld4(hs[L] + (b0+r)*128 + dOwn0);
      float4 b = ld4(hs[L] + (b0+r)*128 + dImp0);
      hO[L][0]=a.x; hO[L][1]=a.y; hO[L][2]=a.z; hO[L][3]=a.w;
      hI[L][0]=b.x; hI[L][1]=b.y; hI[L][2]=b.z; hI[L][3]=b.w;
    }
  }

  // x/m/d pipeline (distance-2 prefetch)
  float4 xP, xC, xN, mC, mN;
  float dhC, dxC, dhN, dxN;
  xC = ld4(x + ((b0+bx)*TT + 0)*VV + v0);
  const float4 x0v = xC;
  xN  = ld4(x  + ((b0+bx)*TT + 1)*VV + v0);
  mN  = ld4(m1 + ((b0+bx)*TT + 1)*VV + v0);
  dhN = dd[(b0+r)*TT + 1];
  dxN = dd[(b0+bx)*TT + 1];
  xP = xC; mC = mN; dhC = dhN; dxC = dxN;  // placeholders, unused at t=0

  __syncthreads();

  float*    const wsP = wsd + pair*(3*2*2*1024);
  unsigned* const wfP = wsf + pair*(3*2*4);
  const int idx0 = r*64 + w*16 + 4*q;   // [b][d-off] within a 16x64 f32 half-slot

  for (int t = 0; t <= TT; ++t){
    const int par = t & 1;
    // ================= phase 1: build fragments =================
    if (t == 0){
      #pragma unroll
      for (int L = 0; L < 3; ++L){
        fragW(&sHP[par][L][0], dOwn0, r, hO[L]);
        fragW(&sHP[par][L][0], dImp0, r, hI[L]);
      }
      fragW(&sH3F[par][0], dOwn0, r, hO[2]);
      fragW(&sH3F[par][0], dImp0, r, hI[2]);
      float xi[4] = {xC.x, xC.y, xC.z, xC.w};
      fragW(&sX1[par][0], v0, bx, xi);
    } else {
      // undecayed h3(t-1) for the head
      fragW(&sH3F[par][0], dOwn0, r, hO[2]);
      fragW(&sH3F[par][0], dImp0, r, hI[2]);
      if (t < TT){
        float gO[4], gI[4];
        #pragma unroll
        for (int e = 0; e < 4; ++e){
          gO[e] = __expf(-fmaxf(dhC*WdhO[e] + bdhO[e], 0.f));
          gI[e] = __expf(-fmaxf(dhC*WdhI[e] + bdhI[e], 0.f));
        }
        #pragma unroll
        for (int L = 0; L < 3; ++L){
          #pragma unroll
          for (int e = 0; e < 4; ++e){ hO[L][e] *= gO[e]; hI[L][e] *= gI[e]; }
          fragW(&sHP[par][L][0], dOwn0, r, hO[L]);
          fragW(&sHP[par][L][0], dImp0, r, hI[L]);
        }
        float xi[4];
        const float* xc = (const float*)&xC; const float* xp = (const float*)&xP;
        const float* x0e = (const float*)&x0v; const float* me = (const float*)&mC;
        #pragma unroll
        for (int e = 0; e < 4; ++e){
          float gx = __expf(-fmaxf(dxC*Wdx4[e] + bdx4[e], 0.f));
          xi[e] = (xp[e]*gx + (1.f-gx)*x0e[e])*(1.f-me[e]) + me[e]*xc[e];
        }
        fragW(&sX1[par][0], v0, bx, xi);
      }
    }
    barrier_lds();   // A

    // ================= head: y[t-1] =================
    if (t >= 1 && half == 0 && w == 0){
      f32x4v cl = {0.f,0.f,0.f,0.f};
      #pragma unroll
      for (int kt = 0; kt < 4; ++kt)
        cl = MFMA(aO[kt], sH3F[par][kt*64 + lane], cl);
      if (lane < 16){
        float l0 = cl[0]+bo4[0], l1 = cl[1]+bo4[1], l2 = cl[2]+bo4[2], l3 = cl[3]+bo4[3];
        float mx = fmaxf(fmaxf(l0,l1), fmaxf(l2,l3));
        float e0 = __expf(l0-mx), e1 = __expf(l1-mx), e2 = __expf(l2-mx), e3 = __expf(l3-mx);
        float inv = 1.f/(e0+e1+e2+e3);
        float4 o; o.x = e0*inv; o.y = e1*inv; o.z = e2*inv; o.w = e3*inv;
        *(float4*)(y + ((b0+lane)*TT + (t-1))*4) = o;
      }
    }

    if (t < TT){
      // ================= layer 1 =================
      f32x4v Ci[3], Ch[3];
      #pragma unroll
      for (int g = 0; g < 3; ++g){ Ci[g] = (f32x4v){0.f,0.f,0.f,0.f}; Ch[g] = (f32x4v){0.f,0.f,0.f,0.f}; }
      f16x8 bx1[2], bh1[4];
      #pragma unroll
      for (int kt = 0; kt < 2; ++kt) bx1[kt] = sX1[par][kt*64 + lane];
      #pragma unroll
      for (int kt = 0; kt < 4; ++kt) bh1[kt] = sHP[par][0][kt*64 + lane];
      #pragma unroll
      for (int g = 0; g < 3; ++g){
        #pragma unroll
        for (int kt = 0; kt < 2; ++kt) Ci[g] = MFMA(Ai1[g][kt], bx1[kt], Ci[g]);
        #pragma unroll
        for (int kt = 0; kt < 4; ++kt) Ch[g] = MFMA(Ah1[g][kt], bh1[kt], Ch[g]);
      }
      gates_upd(Ci, Ch, &sBRZ[0][dOwn0], &sBRZ[0][128+dOwn0], &sBN[0][0][dOwn0], &sBN[0][1][dOwn0], hO[0]);
      fragW(&sH1F[0], dOwn0, r, hO[0]);
      publish4(wsP + ((0*2+half)*2+par)*1024, idx0, hO[0]);
      // Ch2 cover (independent of h1) hides the exchange latency
      f32x4v C2h[3];
      #pragma unroll
      for (int g = 0; g < 3; ++g) C2h[g] = (f32x4v){0.f,0.f,0.f,0.f};
      f16x8 bh2[4];
      #pragma unroll
      for (int kt = 0; kt < 4; ++kt) bh2[kt] = sHP[par][1][kt*64 + lane];
      #pragma unroll
      for (int g = 0; g < 3; ++g)
        #pragma unroll
        for (int kt = 0; kt < 4; ++kt) C2h[g] = MFMA(Ah2[g][kt], bh2[kt], C2h[g]);
      wait_vm0();
      if (lane == 0) AT_ST(wfP + (0*2+half)*4 + w, (unsigned)(t+1));
      spin_on(wfP + (0*2+(1-half))*4 + w, (unsigned)(t+1));
      import4(wsP + ((0*2+(1-half))*2+par)*1024, idx0, hI[0]);
      fragW(&sH1F[0], dImp0, r, hI[0]);
      barrier_lds();  // B1

      // ================= layer 2 =================
      f32x4v C2i[3];
      #pragma unroll
      for (int g = 0; g < 3; ++g) C2i[g] = (f32x4v){0.f,0.f,0.f,0.f};
      f16x8 b1f[4];
      #pragma unroll
      for (int kt = 0; kt < 4; ++kt) b1f[kt] = sH1F[kt*64 + lane];
      #pragma unroll
      for (int g = 0; g < 3; ++g)
        #pragma unroll
        for (int kt = 0; kt < 4; ++kt) C2i[g] = MFMA(Ai2[g][kt], b1f[kt], C2i[g]);
      gates_upd(C2i, C2h, &sBRZ[1][dOwn0], &sBRZ[1][128+dOwn0], &sBN[1][0][dOwn0], &sBN[1][1][dOwn0], hO[1]);
      fragW(&sH2F[0], dOwn0, r, hO[1]);
      publish4(wsP + ((1*2+half)*2+par)*1024, idx0, hO[1]);
      // Ch3 cover
      f32x4v C3h[3];
      #pragma unroll
      for (int g = 0; g < 3; ++g) C3h[g] = (f32x4v){0.f,0.f,0.f,0.f};
      f16x8 bh3[4];
      #pragma unroll
      for (int kt = 0; kt < 4; ++kt) bh3[kt] = sHP[par][2][kt*64 + lane];
      #pragma unroll
      for (int g = 0; g < 3; ++g)
        #pragma unroll
        for (int kt = 0; kt < 4; ++kt) C3h[g] = MFMA(Ah3[g][kt], bh3[kt], C3h[g]);
      wait_vm0();
      if (lane == 0) AT_ST(wfP + (1*2+half)*4 + w, (unsigned)(t+1));
      spin_on(wfP + (1*2+(1-half))*4 + w, (unsigned)(t+1));
      import4(wsP + ((1*2+(1-half))*2+par)*1024, idx0, hI[1]);
      fragW(&sH2F[0], dImp0, r, hI[1]);
      barrier_lds();  // B2

      // ================= layer 3 =================
      f32x4v C3i[3];
      #pragma unroll
      for (int g = 0; g < 3; ++g) C3i[g] = (f32x4v){0.f,0.f,0.f,0.f};
      f16x8 b2f[4];
      #pragma unroll
      for (int kt = 0; kt < 4; ++kt) b2f[kt] = sH2F[kt*64 + lane];
      #pragma unroll
      for (int g = 0; g < 3; ++g)
        #pragma unroll
        for (int kt = 0; kt < 4; ++kt) C3i[g] = MFMA(Ai3[g][kt], b2f[kt], C3i[g]);
      gates_upd(C3i, C3h, &sBRZ[2][dOwn0], &sBRZ[2][128+dOwn0], &sBN[2][0][dOwn0], &sBN[2][1][dOwn0], hO[2]);
      publish4(wsP + ((2*2+half)*2+par)*1024, idx0, hO[2]);
      wait_vm0();
      if (lane == 0) AT_ST(wfP + (2*2+half)*4 + w, (unsigned)(t+1));
      spin_on(wfP + (2*2+(1-half))*4 + w, (unsigned)(t+1));
      import4(wsP + ((2*2+(1-half))*2+par)*1024, idx0, hI[2]);

      // rotate + distance-2 prefetch (issued in the largest inter-waitcnt gap)
      xP = xC; xC = xN; mC = mN; dhC = dhN; dxC = dxN;
      const int tp = (t+2 < TT) ? (t+2) : (TT-1);
      xN  = ld4(x  + ((b0+bx)*TT + tp)*VV + v0);
      mN  = ld4(m1 + ((b0+bx)*TT + tp)*VV + v0);
      dhN = dd[(b0+r)*TT + tp];
      dxN = dd[(b0+bx)*TT + tp];
    }
  }
}

extern "C" void kernel_launch(void* const* d_in, const int* in_sizes, int n_in,
                              void* d_out, int out_size, void* d_ws, size_t ws_size,
                              hipStream_t stream) {
  (void)in_sizes; (void)n_in; (void)out_size; (void)ws_size;
  float* wsd = (float*)d_ws;
  unsigned* wsf = (unsigned*)((char*)d_ws + (size_t)32*3*2*2*1024*4);  // 1.5 MB data, then flags
  k_grud<<<dim3(64), dim3(256), 0, stream>>>(
      (const float*)d_in[0],  (const float*)d_in[1],  (const float*)d_in[2],
      (const float*)d_in[3],  (const float*)d_in[4],  (const float*)d_in[5],
      (const float*)d_in[6],  (const float*)d_in[7],  (const float*)d_in[8],  (const float*)d_in[9],
      (const float*)d_in[10], (const float*)d_in[11], (const float*)d_in[12], (const float*)d_in[13],
      (const float*)d_in[14], (const float*)d_in[15], (const float*)d_in[16], (const float*)d_in[17],
      (const float*)d_in[18], (const float*)d_in[19],
      (const float*)d_in[20], (const float*)d_in[21],
      (const float*)d_in[22], (const float*)d_in[23],
      (float*)d_out, wsd, wsf);
}

// Round 2
// 1793.337 us; speedup vs baseline: 3.7964x; 3.7964x over previous
//
#include <hip/hip_runtime.h>

#define TT 512
#define VV 64

typedef _Float16 f16;
typedef f16 f16x8 __attribute__((ext_vector_type(8)));
typedef f16 f16x4 __attribute__((ext_vector_type(4)));
typedef float f32x4v __attribute__((ext_vector_type(4)));
typedef unsigned long long u64;
typedef unsigned u32;

#define MFMA(A_,B_,C_) __builtin_amdgcn_mfma_f32_16x16x32_f16((A_),(B_),(C_),0,0,0)
#define AT_LD32(p)   __hip_atomic_load((p), __ATOMIC_RELAXED, __HIP_MEMORY_SCOPE_AGENT)
#define AT_ST32(p,v) __hip_atomic_store((p),(v), __ATOMIC_RELAXED, __HIP_MEMORY_SCOPE_AGENT)
#define AT_LD64(p)   __hip_atomic_load((p), __ATOMIC_RELAXED, __HIP_MEMORY_SCOPE_AGENT)
#define AT_ST64(p,v) __hip_atomic_store((p),(v), __ATOMIC_RELAXED, __HIP_MEMORY_SCOPE_AGENT)

__device__ __forceinline__ void barrier_lds(){ asm volatile("s_waitcnt lgkmcnt(0)\n\ts_barrier" ::: "memory"); }
__device__ __forceinline__ void wait_vm0(){ asm volatile("s_waitcnt vmcnt(0)" ::: "memory"); }
__device__ __forceinline__ float4 ld4(const float* p){ return *(const float4*)p; }

__device__ __forceinline__ f16x8 ldA8(const float* p){
  f16x8 a;
  #pragma unroll
  for (int j = 0; j < 8; ++j) a[j] = (f16)p[j];
  return a;
}

// element offset (in f16 units) of (k=d0..d0+3, col=b) inside a B-frag buffer
// layout: [kt][lane'][j], lane' = ((d&31)>>3)*16 + b, j = d&7
__device__ __forceinline__ int fragOff16(int d0, int b){
  const int kt = d0 >> 5, qq = (d0 >> 3) & 3, j0 = d0 & 7;
  return (kt*64 + qq*16 + b)*8 + j0;
}

__device__ __forceinline__ void fragW_lds(f16x8* buf, int d0, int b, const float* h4){
  f16x4 v;
  #pragma unroll
  for (int e = 0; e < 4; ++e) v[e] = (f16)h4[e];
  *(f16x4*)((f16*)buf + fragOff16(d0, b)) = v;
}

__device__ __forceinline__ void pubFrag(char* slot, int d0, int b, const float* h4){
  union { f16x4 v; u64 u; } uu;
  #pragma unroll
  for (int e = 0; e < 4; ++e) uu.v[e] = (f16)h4[e];
  AT_ST64((u64*)(slot + fragOff16(d0, b)*2), uu.u);
}

__device__ __forceinline__ f16x8 impFrag(const char* slot, int kt, int lane){
  union { u64 u[2]; f16x8 v; } vv;
  const u64* p = (const u64*)(slot + (kt*64 + lane)*16);
  vv.u[0] = AT_LD64((u64*)p);
  vv.u[1] = AT_LD64((u64*)(p + 1));
  return vv.v;
}

__device__ __forceinline__ void spin_ge(u32* f, u32 val){
  if ((threadIdx.x & 63) == 0){
    u32 g = 0;
    while (AT_LD32(f) < val && ++g < (1u << 20)) {}
  }
  asm volatile("" ::: "memory");
}

__device__ __forceinline__ void gates_upd(const f32x4v* Ci, const f32x4v* Ch,
                                          const float* bR, const float* bZ,
                                          const float* bI, const float* bH,
                                          float* hp){
  #pragma unroll
  for (int e = 0; e < 4; ++e){
    float rr = 1.f/(1.f + __expf(-(Ci[0][e] + Ch[0][e] + bR[e])));
    float zz = 1.f/(1.f + __expf(-(Ci[1][e] + Ch[1][e] + bZ[e])));
    float nv = Ci[2][e] + bI[e] + rr*(Ch[2][e] + bH[e]);
    float nn = 1.f - 2.f/(1.f + __expf(2.f*nv));
    hp[e] = (1.f - zz)*nn + zz*hp[e];
  }
}

__global__ void k_init(u32* wsf){
  const int i = blockIdx.x*256 + threadIdx.x;
  if (i < 4096) AT_ST32(wsf + i, 0u);
}

// roles: 0=L1 (x-path, produce ch0), 1=L2 (ch0->ch1), 2=L3 (ch1->ch2), 3=head (consume ch2)
__launch_bounds__(256, 1)
__global__ void k_pipe(const float* __restrict__ x,   const float* __restrict__ dd,
                       const float* __restrict__ m1,
                       const float* __restrict__ h01, const float* __restrict__ h02,
                       const float* __restrict__ h03,
                       const float* __restrict__ Wih1, const float* __restrict__ Whh1,
                       const float* __restrict__ bih1, const float* __restrict__ bhh1,
                       const float* __restrict__ Wih2, const float* __restrict__ Whh2,
                       const float* __restrict__ bih2, const float* __restrict__ bhh2,
                       const float* __restrict__ Wih3, const float* __restrict__ Whh3,
                       const float* __restrict__ bih3, const float* __restrict__ bhh3,
                       const float* __restrict__ Wout, const float* __restrict__ bout,
                       const float* __restrict__ Wdx,  const float* __restrict__ bdx,
                       const float* __restrict__ Wdh,  const float* __restrict__ bdh,
                       float* __restrict__ y, u32* __restrict__ wsf, char* __restrict__ wsd)
{
  __shared__ f16x8 sFrag[256];
  __shared__ f16x8 sX1[128];
  __shared__ float sBRZ[256];
  __shared__ float sBN0[128], sBN1[128];

  const int tid = threadIdx.x, w = tid >> 6, lane = tid & 63;
  const int q = lane >> 4, r = lane & 15;
  const int blk = blockIdx.x, role = blk >> 5, grp = blk & 31, b0 = grp << 4;

  u32* const FL  = wsf;            // flag[chan*32+grp] at stride 16 dwords
  u32* const ACK = wsf + 1536;

#define SLOT(ch,s) (wsd + (size_t)((((ch)*32 + grp)*4 + (s)))*4096)
#define FLP(ch)    (FL  + ((ch)*32 + grp)*16)
#define ACKP(ch)   (ACK + ((ch)*32 + grp)*16)

  // ===================== head =====================
  if (role == 3){
    if (w) return;
    f16x8 aO[4];
    #pragma unroll
    for (int kt = 0; kt < 4; ++kt){
      f16x8 a;
      #pragma unroll
      for (int j = 0; j < 8; ++j)
        a[j] = (r < 4) ? (f16)Wout[r*128 + kt*32 + q*8 + j] : (f16)0.f;
      aO[kt] = a;
    }
    float bo4[4];
    #pragma unroll
    for (int e = 0; e < 4; ++e) bo4[e] = bout[e];
    for (int t = 0; t < TT; ++t){
      spin_ge(FLP(2), (u32)(t+1));
      const char* sIn = SLOT(2, t & 3);
      f32x4v cl = {0.f,0.f,0.f,0.f};
      #pragma unroll
      for (int kt = 0; kt < 4; ++kt) cl = MFMA(aO[kt], impFrag(sIn, kt, lane), cl);
      if (lane < 16){
        float l0 = cl[0]+bo4[0], l1 = cl[1]+bo4[1], l2 = cl[2]+bo4[2], l3 = cl[3]+bo4[3];
        float mx = fmaxf(fmaxf(l0,l1), fmaxf(l2,l3));
        float e0 = __expf(l0-mx), e1 = __expf(l1-mx), e2 = __expf(l2-mx), e3 = __expf(l3-mx);
        float inv = 1.f/(e0+e1+e2+e3);
        float4 o; o.x = e0*inv; o.y = e1*inv; o.z = e2*inv; o.w = e3*inv;
        *(float4*)(y + ((size_t)(b0+lane)*TT + t)*4) = o;
      }
      if (lane == 0) AT_ST32(ACKP(2), (u32)(t+1));
    }
    return;
  }

  // ===================== L1 =====================
  if (role == 0){
    sBRZ[tid] = bih1[tid] + bhh1[tid];
    if (tid < 128){ sBN0[tid] = bih1[256+tid]; sBN1[tid] = bhh1[256+tid]; }

    f16x8 Ai[2][3][2], Ah[2][3][4];
    #pragma unroll
    for (int G = 0; G < 2; ++G){
      const int G16 = w + 4*G;
      #pragma unroll
      for (int g = 0; g < 3; ++g){
        const int mrow = (g*8 + G16)*16 + r;
        #pragma unroll
        for (int kt = 0; kt < 2; ++kt) Ai[G][g][kt] = ldA8(Wih1 + mrow*64 + kt*32 + q*8);
        #pragma unroll
        for (int kt = 0; kt < 4; ++kt) Ah[G][g][kt] = ldA8(Whh1 + mrow*128 + kt*32 + q*8);
      }
    }
    float hS[2][4], WdhL[2][4], bdhL[2][4];
    #pragma unroll
    for (int G = 0; G < 2; ++G){
      const int dG = (w + 4*G)*16 + 4*q;
      float4 a = ld4(h01 + (size_t)(b0+r)*128 + dG);
      hS[G][0]=a.x; hS[G][1]=a.y; hS[G][2]=a.z; hS[G][3]=a.w;
      #pragma unroll
      for (int e = 0; e < 4; ++e){ WdhL[G][e] = Wdh[dG+e]; bdhL[G][e] = bdh[dG+e]; }
    }
    const int bx = w*4 + q, v0 = 4*r;
    float Wdx4[4], bdx4[4];
    #pragma unroll
    for (int e = 0; e < 4; ++e){ Wdx4[e] = Wdx[v0+e]; bdx4[e] = bdx[v0+e]; }

    float4 xC = ld4(x + ((size_t)(b0+bx)*TT + 0)*VV + v0);
    const float4 x0v = xC;
    float4 xN = ld4(x  + ((size_t)(b0+bx)*TT + 1)*VV + v0);
    float4 mN = ld4(m1 + ((size_t)(b0+bx)*TT + 1)*VV + v0);
    float dhN = dd[(size_t)(b0+r)*TT + 1];
    float dxN = dd[(size_t)(b0+bx)*TT + 1];
    float4 xP = xC, mC = mN; float dhC = dhN, dxC = dxN;
    __syncthreads();

    for (int t = 0; t < TT; ++t){
      if (t >= 4) spin_ge(ACKP(0), (u32)(t-3));
      float xi[4];
      if (t == 0){ xi[0]=xC.x; xi[1]=xC.y; xi[2]=xC.z; xi[3]=xC.w; }
      else {
        const float* xc = (const float*)&xC; const float* xp = (const float*)&xP;
        const float* x0e = (const float*)&x0v; const float* me = (const float*)&mC;
        #pragma unroll
        for (int e = 0; e < 4; ++e){
          float gx = __expf(-fmaxf(dxC*Wdx4[e] + bdx4[e], 0.f));
          xi[e] = (xp[e]*gx + (1.f-gx)*x0e[e])*(1.f-me[e]) + me[e]*xc[e];
        }
      }
      fragW_lds(sX1, v0, bx, xi);
      #pragma unroll
      for (int G = 0; G < 2; ++G){
        const int dG = (w + 4*G)*16 + 4*q;
        if (t >= 1){
          #pragma unroll
          for (int e = 0; e < 4; ++e){
            float gh = __expf(-fmaxf(dhC*WdhL[G][e] + bdhL[G][e], 0.f));
            hS[G][e] *= gh;
          }
        }
        fragW_lds(sFrag, dG, r, hS[G]);
      }
      barrier_lds();
      f16x8 bx1[2], bh4[4];
      #pragma unroll
      for (int kt = 0; kt < 2; ++kt) bx1[kt] = sX1[kt*64 + lane];
      #pragma unroll
      for (int kt = 0; kt < 4; ++kt) bh4[kt] = sFrag[kt*64 + lane];
      f32x4v Ci[2][3], Ch[2][3];
      #pragma unroll
      for (int G = 0; G < 2; ++G)
        #pragma unroll
        for (int g = 0; g < 3; ++g){ Ci[G][g] = (f32x4v){0,0,0,0}; Ch[G][g] = (f32x4v){0,0,0,0}; }
      #pragma unroll
      for (int G = 0; G < 2; ++G)
        #pragma unroll
        for (int g = 0; g < 3; ++g){
          #pragma unroll
          for (int kt = 0; kt < 4; ++kt) Ch[G][g] = MFMA(Ah[G][g][kt], bh4[kt], Ch[G][g]);
          #pragma unroll
          for (int kt = 0; kt < 2; ++kt) Ci[G][g] = MFMA(Ai[G][g][kt], bx1[kt], Ci[G][g]);
        }
      char* sOut = SLOT(0, t & 3);
      #pragma unroll
      for (int G = 0; G < 2; ++G){
        const int dG = (w + 4*G)*16 + 4*q;
        gates_upd(&Ci[G][0], &Ch[G][0], &sBRZ[dG], &sBRZ[128+dG], &sBN0[dG], &sBN1[dG], hS[G]);
        pubFrag(sOut, dG, r, hS[G]);
      }
      wait_vm0();
      barrier_lds();
      if (tid == 0) AT_ST32(FLP(0), (u32)(t+1));
      xP = xC; xC = xN; mC = mN; dhC = dhN; dxC = dxN;
      const int tp = (t+2 < TT) ? (t+2) : (TT-1);
      xN  = ld4(x  + ((size_t)(b0+bx)*TT + tp)*VV + v0);
      mN  = ld4(m1 + ((size_t)(b0+bx)*TT + tp)*VV + v0);
      dhN = dd[(size_t)(b0+r)*TT + tp];
      dxN = dd[(size_t)(b0+bx)*TT + tp];
    }
    return;
  }

  // ===================== L2 / L3 =====================
  {
    const float* Wihp = (role == 1) ? Wih2 : Wih3;
    const float* Whhp = (role == 1) ? Whh2 : Whh3;
    const float* bip  = (role == 1) ? bih2 : bih3;
    const float* bhp  = (role == 1) ? bhh2 : bhh3;
    const float* h0p  = (role == 1) ? h02  : h03;
    const int cIn = role - 1, cOut = role;

    sBRZ[tid] = bip[tid] + bhp[tid];
    if (tid < 128){ sBN0[tid] = bip[256+tid]; sBN1[tid] = bhp[256+tid]; }

    f16x8 Ai[2][3][4], Ah[2][3][4];
    #pragma unroll
    for (int G = 0; G < 2; ++G){
      const int G16 = w + 4*G;
      #pragma unroll
      for (int g = 0; g < 3; ++g){
        const int mrow = (g*8 + G16)*16 + r;
        #pragma unroll
        for (int kt = 0; kt < 4; ++kt){
          Ai[G][g][kt] = ldA8(Wihp + mrow*128 + kt*32 + q*8);
          Ah[G][g][kt] = ldA8(Whhp + mrow*128 + kt*32 + q*8);
        }
      }
    }
    float hS[2][4], WdhL[2][4], bdhL[2][4];
    #pragma unroll
    for (int G = 0; G < 2; ++G){
      const int dG = (w + 4*G)*16 + 4*q;
      float4 a = ld4(h0p + (size_t)(b0+r)*128 + dG);
      hS[G][0]=a.x; hS[G][1]=a.y; hS[G][2]=a.z; hS[G][3]=a.w;
      #pragma unroll
      for (int e = 0; e < 4; ++e){ WdhL[G][e] = Wdh[dG+e]; bdhL[G][e] = bdh[dG+e]; }
    }
    float dhC = 0.f, dhN = dd[(size_t)(b0+r)*TT + 1];
    __syncthreads();

    for (int t = 0; t < TT; ++t){
      spin_ge(FLP(cIn), (u32)(t+1));
      const char* sIn = SLOT(cIn, t & 3);
      f16x8 bi4[4];
      #pragma unroll
      for (int kt = 0; kt < 4; ++kt) bi4[kt] = impFrag(sIn, kt, lane);
      if (t >= 4) spin_ge(ACKP(cOut), (u32)(t-3));
      #pragma unroll
      for (int G = 0; G < 2; ++G){
        const int dG = (w + 4*G)*16 + 4*q;
        if (t >= 1){
          #pragma unroll
          for (int e = 0; e < 4; ++e){
            float gh = __expf(-fmaxf(dhC*WdhL[G][e] + bdhL[G][e], 0.f));
            hS[G][e] *= gh;
          }
        }
        fragW_lds(sFrag, dG, r, hS[G]);
      }
      barrier_lds();
      f16x8 bh4[4];
      #pragma unroll
      for (int kt = 0; kt < 4; ++kt) bh4[kt] = sFrag[kt*64 + lane];
      f32x4v Ci[2][3], Ch[2][3];
      #pragma unroll
      for (int G = 0; G < 2; ++G)
        #pragma unroll
        for (int g = 0; g < 3; ++g){ Ci[G][g] = (f32x4v){0,0,0,0}; Ch[G][g] = (f32x4v){0,0,0,0}; }
      #pragma unroll
      for (int G = 0; G < 2; ++G)
        #pragma unroll
        for (int g = 0; g < 3; ++g){
          #pragma unroll
          for (int kt = 0; kt < 4; ++kt) Ch[G][g] = MFMA(Ah[G][g][kt], bh4[kt], Ch[G][g]);
          #pragma unroll
          for (int kt = 0; kt < 4; ++kt) Ci[G][g] = MFMA(Ai[G][g][kt], bi4[kt], Ci[G][g]);
        }
      char* sOut = SLOT(cOut, t & 3);
      #pragma unroll
      for (int G = 0; G < 2; ++G){
        const int dG = (w + 4*G)*16 + 4*q;
        gates_upd(&Ci[G][0], &Ch[G][0], &sBRZ[dG], &sBRZ[128+dG], &sBN0[dG], &sBN1[dG], hS[G]);
        pubFrag(sOut, dG, r, hS[G]);
      }
      wait_vm0();
      barrier_lds();
      if (tid == 0){ AT_ST32(FLP(cOut), (u32)(t+1)); AT_ST32(ACKP(cIn), (u32)(t+1)); }
      dhC = dhN;
      const int tp = (t+2 < TT) ? (t+2) : (TT-1);
      dhN = dd[(size_t)(b0+r)*TT + tp];
    }
  }
}

extern "C" void kernel_launch(void* const* d_in, const int* in_sizes, int n_in,
                              void* d_out, int out_size, void* d_ws, size_t ws_size,
                              hipStream_t stream) {
  (void)in_sizes; (void)n_in; (void)out_size; (void)ws_size;
  u32*  wsf = (u32*)d_ws;
  char* wsd = (char*)d_ws + 16384;
  k_init<<<dim3(16), dim3(256), 0, stream>>>(wsf);
  k_pipe<<<dim3(128), dim3(256), 0, stream>>>(
      (const float*)d_in[0],  (const float*)d_in[1],  (const float*)d_in[2],
      (const float*)d_in[3],  (const float*)d_in[4],  (const float*)d_in[5],
      (const float*)d_in[6],  (const float*)d_in[7],  (const float*)d_in[8],  (const float*)d_in[9],
      (const float*)d_in[10], (const float*)d_in[11], (const float*)d_in[12], (const float*)d_in[13],
      (const float*)d_in[14], (const float*)d_in[15], (const float*)d_in[16], (const float*)d_in[17],
      (const float*)d_in[18], (const float*)d_in[19],
      (const float*)d_in[20], (const float*)d_in[21],
      (const float*)d_in[22], (const float*)d_in[23],
      (float*)d_out, wsf, wsd);
}

// Round 3
// 1527.076 us; speedup vs baseline: 4.4583x; 1.1744x over previous
//
#include <hip/hip_runtime.h>

#define TT 512
#define VV 64

typedef _Float16 f16;
typedef f16 f16x8 __attribute__((ext_vector_type(8)));
typedef f16 f16x4 __attribute__((ext_vector_type(4)));
typedef float f32x4v __attribute__((ext_vector_type(4)));
typedef unsigned long long u64;
typedef unsigned u32;

#define MFMA(A_,B_,C_) __builtin_amdgcn_mfma_f32_16x16x32_f16((A_),(B_),(C_),0,0,0)
#define AT_LD32(p)   __hip_atomic_load((p), __ATOMIC_RELAXED, __HIP_MEMORY_SCOPE_AGENT)
#define AT_ST32(p,v) __hip_atomic_store((p),(v), __ATOMIC_RELAXED, __HIP_MEMORY_SCOPE_AGENT)
#define AT_LD64(p)   __hip_atomic_load((p), __ATOMIC_RELAXED, __HIP_MEMORY_SCOPE_AGENT)
#define AT_ST64(p,v) __hip_atomic_store((p),(v), __ATOMIC_RELAXED, __HIP_MEMORY_SCOPE_AGENT)

__device__ __forceinline__ void barrier_lds(){ asm volatile("s_waitcnt lgkmcnt(0)\n\ts_barrier" ::: "memory"); }
__device__ __forceinline__ void wait_vm0(){ asm volatile("s_waitcnt vmcnt(0)" ::: "memory"); }
__device__ __forceinline__ float4 ld4(const float* p){ return *(const float4*)p; }

__device__ __forceinline__ f16x8 ldA8(const float* p){
  f16x8 a;
  #pragma unroll
  for (int j = 0; j < 8; ++j) a[j] = (f16)p[j];
  return a;
}

// element offset (in f16 units) of (k=d0..d0+3, col=b) inside a B-frag buffer
// layout: [kt][lane'][j], lane' = ((d&31)>>3)*16 + b, j = d&7
__device__ __forceinline__ int fragOff16(int d0, int b){
  const int kt = d0 >> 5, qq = (d0 >> 3) & 3, j0 = d0 & 7;
  return (kt*64 + qq*16 + b)*8 + j0;
}

__device__ __forceinline__ void fragW_lds(f16x8* buf, int d0, int b, const float* h4){
  f16x4 v;
  #pragma unroll
  for (int e = 0; e < 4; ++e) v[e] = (f16)h4[e];
  *(f16x4*)((f16*)buf + fragOff16(d0, b)) = v;
}

__device__ __forceinline__ void pubFrag(char* slot, int d0, int b, const float* h4){
  union { f16x4 v; u64 u; } uu;
  #pragma unroll
  for (int e = 0; e < 4; ++e) uu.v[e] = (f16)h4[e];
  AT_ST64((u64*)(slot + fragOff16(d0, b)*2), uu.u);
}

__device__ __forceinline__ f16x8 impFrag(const char* slot, int kt, int lane){
  union { u64 u[2]; f16x8 v; } vv;
  const u64* p = (const u64*)(slot + (kt*64 + lane)*16);
  vv.u[0] = AT_LD64((u64*)p);
  vv.u[1] = AT_LD64((u64*)(p + 1));
  return vv.v;
}

__device__ __forceinline__ void spin_ge(u32* f, u32 val){
  if ((threadIdx.x & 63) == 0){
    u32 g = 0;
    while (AT_LD32(f) < val && ++g < (1u << 20)) {}
  }
  asm volatile("" ::: "memory");
}

__device__ __forceinline__ void gates_upd(const f32x4v* Ci, const f32x4v* Ch,
                                          const float* bR, const float* bZ,
                                          const float* bI, const float* bH,
                                          float* hp){
  #pragma unroll
  for (int e = 0; e < 4; ++e){
    float rr = 1.f/(1.f + __expf(-(Ci[0][e] + Ch[0][e] + bR[e])));
    float zz = 1.f/(1.f + __expf(-(Ci[1][e] + Ch[1][e] + bZ[e])));
    float nv = Ci[2][e] + bI[e] + rr*(Ch[2][e] + bH[e]);
    float nn = 1.f - 2.f/(1.f + __expf(2.f*nv));
    hp[e] = (1.f - zz)*nn + zz*hp[e];
  }
}

__global__ void k_init(u32* wsf){
  const int i = blockIdx.x*256 + threadIdx.x;
  if (i < 4096) AT_ST32(wsf + i, 0u);
}

// roles: 0=L1 (x-path -> ch0), 1=L2 (ch0->ch1), 2=L3+head (ch1 -> y)
__launch_bounds__(256, 1)
__global__ void k_pipe(const float* __restrict__ x,   const float* __restrict__ dd,
                       const float* __restrict__ m1,
                       const float* __restrict__ h01, const float* __restrict__ h02,
                       const float* __restrict__ h03,
                       const float* __restrict__ Wih1, const float* __restrict__ Whh1,
                       const float* __restrict__ bih1, const float* __restrict__ bhh1,
                       const float* __restrict__ Wih2, const float* __restrict__ Whh2,
                       const float* __restrict__ bih2, const float* __restrict__ bhh2,
                       const float* __restrict__ Wih3, const float* __restrict__ Whh3,
                       const float* __restrict__ bih3, const float* __restrict__ bhh3,
                       const float* __restrict__ Wout, const float* __restrict__ bout,
                       const float* __restrict__ Wdx,  const float* __restrict__ bdx,
                       const float* __restrict__ Wdh,  const float* __restrict__ bdh,
                       float* __restrict__ y, u32* __restrict__ wsf, char* __restrict__ wsd)
{
  __shared__ f16x8 sFrag[2][256];
  __shared__ f16x8 sX1[2][128];
  __shared__ f16x8 sHead[2][256];

  const int tid = threadIdx.x, w = tid >> 6, lane = tid & 63;
  const int q = lane >> 4, r = lane & 15;
  const int blk = blockIdx.x, role = blk >> 5, grp = blk & 31, b0 = grp << 4;

  u32* const FL  = wsf;
  u32* const ACK = wsf + 1024;

#define SLOT(ch,s) (wsd + (size_t)((((ch)*32 + grp)*8 + (s)))*4096)
#define FLP(ch)    (FL  + ((ch)*32 + grp)*16)
#define ACKP(ch)   (ACK + ((ch)*32 + grp)*16)

  // ---- per-thread hidden-dim biases (all roles L1..L3) ----
  const float* bihX = (role == 0) ? bih1 : (role == 1) ? bih2 : bih3;
  const float* bhhX = (role == 0) ? bhh1 : (role == 1) ? bhh2 : bhh3;
  const float* h0X  = (role == 0) ? h01  : (role == 1) ? h02  : h03;

  float bR[2][4], bZ[2][4], bI[2][4], bH[2][4];
  float hS[2][4], WdhL[2][4], bdhL[2][4];
  #pragma unroll
  for (int G = 0; G < 2; ++G){
    const int dG = (w + 4*G)*16 + 4*q;
    #pragma unroll
    for (int e = 0; e < 4; ++e){
      const int d = dG + e;
      bR[G][e] = bihX[d] + bhhX[d];
      bZ[G][e] = bihX[128+d] + bhhX[128+d];
      bI[G][e] = bihX[256+d];
      bH[G][e] = bhhX[256+d];
      WdhL[G][e] = Wdh[d]; bdhL[G][e] = bdh[d];
    }
    float4 a = ld4(h0X + (size_t)(b0+r)*128 + dG);
    hS[G][0]=a.x; hS[G][1]=a.y; hS[G][2]=a.z; hS[G][3]=a.w;
  }
  float dhC = 0.f, dhN = dd[(size_t)(b0+r)*TT + 1];

  // ===================== L1 =====================
  if (role == 0){
    f16x8 Ai[2][3][2], Ah[2][3][4];
    #pragma unroll
    for (int G = 0; G < 2; ++G){
      #pragma unroll
      for (int g = 0; g < 3; ++g){
        const int mrow = (g*8 + w + 4*G)*16 + r;
        #pragma unroll
        for (int kt = 0; kt < 2; ++kt) Ai[G][g][kt] = ldA8(Wih1 + mrow*64 + kt*32 + q*8);
        #pragma unroll
        for (int kt = 0; kt < 4; ++kt) Ah[G][g][kt] = ldA8(Whh1 + mrow*128 + kt*32 + q*8);
      }
    }
    const int bx = w*4 + q, v0 = 4*r;
    float Wdx4[4], bdx4[4];
    #pragma unroll
    for (int e = 0; e < 4; ++e){ Wdx4[e] = Wdx[v0+e]; bdx4[e] = bdx[v0+e]; }

    float4 xC = ld4(x + ((size_t)(b0+bx)*TT + 0)*VV + v0);
    const float4 x0v = xC;
    float4 xN = ld4(x  + ((size_t)(b0+bx)*TT + 1)*VV + v0);
    float4 mN = ld4(m1 + ((size_t)(b0+bx)*TT + 1)*VV + v0);
    float dxN = dd[(size_t)(b0+bx)*TT + 1];
    float4 xP = xC, mC = mN; float dxC = dxN;
    __syncthreads();

    for (int t = 0; t < TT; ++t){
      const int par = t & 1;
      if ((t & 3) == 0 && t >= 8) spin_ge(ACKP(0), (u32)(t-4));
      float xi[4];
      if (t == 0){ xi[0]=xC.x; xi[1]=xC.y; xi[2]=xC.z; xi[3]=xC.w; }
      else {
        const float* xc = (const float*)&xC; const float* xp = (const float*)&xP;
        const float* x0e = (const float*)&x0v; const float* me = (const float*)&mC;
        #pragma unroll
        for (int e = 0; e < 4; ++e){
          float gx = __expf(-fmaxf(dxC*Wdx4[e] + bdx4[e], 0.f));
          xi[e] = (xp[e]*gx + (1.f-gx)*x0e[e])*(1.f-me[e]) + me[e]*xc[e];
        }
      }
      fragW_lds(&sX1[par][0], v0, bx, xi);
      #pragma unroll
      for (int G = 0; G < 2; ++G){
        const int dG = (w + 4*G)*16 + 4*q;
        if (t >= 1){
          #pragma unroll
          for (int e = 0; e < 4; ++e)
            hS[G][e] *= __expf(-fmaxf(dhC*WdhL[G][e] + bdhL[G][e], 0.f));
        }
        fragW_lds(&sFrag[par][0], dG, r, hS[G]);
      }
      barrier_lds();
      f16x8 bx1[2], bh4[4];
      #pragma unroll
      for (int kt = 0; kt < 2; ++kt) bx1[kt] = sX1[par][kt*64 + lane];
      #pragma unroll
      for (int kt = 0; kt < 4; ++kt) bh4[kt] = sFrag[par][kt*64 + lane];
      f32x4v Ci[2][3], Ch[2][3];
      #pragma unroll
      for (int G = 0; G < 2; ++G)
        #pragma unroll
        for (int g = 0; g < 3; ++g){ Ci[G][g] = (f32x4v){0,0,0,0}; Ch[G][g] = (f32x4v){0,0,0,0}; }
      #pragma unroll
      for (int G = 0; G < 2; ++G)
        #pragma unroll
        for (int g = 0; g < 3; ++g){
          #pragma unroll
          for (int kt = 0; kt < 4; ++kt) Ch[G][g] = MFMA(Ah[G][g][kt], bh4[kt], Ch[G][g]);
          #pragma unroll
          for (int kt = 0; kt < 2; ++kt) Ci[G][g] = MFMA(Ai[G][g][kt], bx1[kt], Ci[G][g]);
        }
      char* sOut = SLOT(0, t & 7);
      #pragma unroll
      for (int G = 0; G < 2; ++G){
        const int dG = (w + 4*G)*16 + 4*q;
        gates_upd(&Ci[G][0], &Ch[G][0], bR[G], bZ[G], bI[G], bH[G], hS[G]);
        pubFrag(sOut, dG, r, hS[G]);
      }
      if ((t & 3) == 3){
        wait_vm0();
        barrier_lds();
        if (tid == 0) AT_ST32(FLP(0), (u32)(t+1));
      }
      xP = xC; xC = xN; mC = mN; dhC = dhN; dxC = dxN;
      const int tp = (t+2 < TT) ? (t+2) : (TT-1);
      xN  = ld4(x  + ((size_t)(b0+bx)*TT + tp)*VV + v0);
      mN  = ld4(m1 + ((size_t)(b0+bx)*TT + tp)*VV + v0);
      dhN = dd[(size_t)(b0+r)*TT + tp];
      dxN = dd[(size_t)(b0+bx)*TT + tp];
    }
    return;
  }

  // ===================== L2 / L3+head =====================
  {
    const float* Wihp = (role == 1) ? Wih2 : Wih3;
    const float* Whhp = (role == 1) ? Whh2 : Whh3;
    const int cIn = role - 1;

    f16x8 Ai[2][3][4], Ah[2][3][4];
    #pragma unroll
    for (int G = 0; G < 2; ++G){
      #pragma unroll
      for (int g = 0; g < 3; ++g){
        const int mrow = (g*8 + w + 4*G)*16 + r;
        #pragma unroll
        for (int kt = 0; kt < 4; ++kt){
          Ai[G][g][kt] = ldA8(Wihp + mrow*128 + kt*32 + q*8);
          Ah[G][g][kt] = ldA8(Whhp + mrow*128 + kt*32 + q*8);
        }
      }
    }
    // head weights (role 2 only; all waves compute, wave0 stores)
    f16x8 aO[4]; float bo4[4];
    if (role == 2){
      #pragma unroll
      for (int kt = 0; kt < 4; ++kt){
        f16x8 a;
        #pragma unroll
        for (int j = 0; j < 8; ++j)
          a[j] = (r < 4) ? (f16)Wout[r*128 + kt*32 + q*8 + j] : (f16)0.f;
        aO[kt] = a;
      }
      #pragma unroll
      for (int e = 0; e < 4; ++e) bo4[e] = bout[e];
    }
    __syncthreads();

    // preload: wait for first 4 steps, import step 0
    spin_ge(FLP(cIn), 4u);
    f16x8 bi[4];
    #pragma unroll
    for (int kt = 0; kt < 4; ++kt) bi[kt] = impFrag(SLOT(cIn, 0), kt, lane);

    for (int t = 0; t < TT; ++t){
      const int par = t & 1;
      if (role == 1 && (t & 3) == 0 && t >= 8) spin_ge(ACKP(1), (u32)(t-4));
      #pragma unroll
      for (int G = 0; G < 2; ++G){
        const int dG = (w + 4*G)*16 + 4*q;
        if (t >= 1){
          #pragma unroll
          for (int e = 0; e < 4; ++e)
            hS[G][e] *= __expf(-fmaxf(dhC*WdhL[G][e] + bdhL[G][e], 0.f));
        }
        fragW_lds(&sFrag[par][0], dG, r, hS[G]);
      }
      barrier_lds();
      if (role == 1 && tid == 0) AT_ST32(ACKP(0), (u32)t);   // steps <= t-1 fully consumed
      f16x8 bh4[4];
      #pragma unroll
      for (int kt = 0; kt < 4; ++kt) bh4[kt] = sFrag[par][kt*64 + lane];
      f32x4v Ci[2][3], Ch[2][3];
      #pragma unroll
      for (int G = 0; G < 2; ++G)
        #pragma unroll
        for (int g = 0; g < 3; ++g){ Ci[G][g] = (f32x4v){0,0,0,0}; Ch[G][g] = (f32x4v){0,0,0,0}; }
      #pragma unroll
      for (int G = 0; G < 2; ++G)
        #pragma unroll
        for (int g = 0; g < 3; ++g){
          #pragma unroll
          for (int kt = 0; kt < 4; ++kt) Ch[G][g] = MFMA(Ah[G][g][kt], bh4[kt], Ch[G][g]);
          #pragma unroll
          for (int kt = 0; kt < 4; ++kt) Ci[G][g] = MFMA(Ai[G][g][kt], bi[kt], Ci[G][g]);
        }
      #pragma unroll
      for (int G = 0; G < 2; ++G)
        gates_upd(&Ci[G][0], &Ch[G][0], bR[G], bZ[G], bI[G], bH[G], hS[G]);

      if (role == 1){
        char* sOut = SLOT(1, t & 7);
        #pragma unroll
        for (int G = 0; G < 2; ++G){
          const int dG = (w + 4*G)*16 + 4*q;
          pubFrag(sOut, dG, r, hS[G]);
        }
        if ((t & 3) == 3){
          wait_vm0();
          barrier_lds();
          if (tid == 0) AT_ST32(FLP(1), (u32)(t+1));
          if (t < TT-1) spin_ge(FLP(0), (u32)(t+5));
        }
      } else {
        // head: write fresh h3 frags, barrier, MFMA + softmax, store y[., t, .]
        #pragma unroll
        for (int G = 0; G < 2; ++G){
          const int dG = (w + 4*G)*16 + 4*q;
          fragW_lds(&sHead[par][0], dG, r, hS[G]);
        }
        barrier_lds();
        if (tid == 0) AT_ST32(ACKP(1), (u32)(t+1));   // step t consumed
        f32x4v cl = {0.f,0.f,0.f,0.f};
        #pragma unroll
        for (int kt = 0; kt < 4; ++kt) cl = MFMA(aO[kt], sHead[par][kt*64 + lane], cl);
        if (tid < 16){
          float l0 = cl[0]+bo4[0], l1 = cl[1]+bo4[1], l2 = cl[2]+bo4[2], l3 = cl[3]+bo4[3];
          float mx = fmaxf(fmaxf(l0,l1), fmaxf(l2,l3));
          float e0 = __expf(l0-mx), e1 = __expf(l1-mx), e2 = __expf(l2-mx), e3 = __expf(l3-mx);
          float inv = 1.f/(e0+e1+e2+e3);
          float4 o; o.x = e0*inv; o.y = e1*inv; o.z = e2*inv; o.w = e3*inv;
          *(float4*)(y + ((size_t)(b0+tid)*TT + t)*4) = o;
        }
        if ((t & 3) == 3 && t < TT-1) spin_ge(FLP(1), (u32)(t+5));
      }

      // import next step's input frags (slot validity covered by amortized spins)
      if (t < TT-1){
        const char* sIn = SLOT(cIn, (t+1) & 7);
        #pragma unroll
        for (int kt = 0; kt < 4; ++kt) bi[kt] = impFrag(sIn, kt, lane);
      }
      dhC = dhN;
      const int tp = (t+2 < TT) ? (t+2) : (TT-1);
      dhN = dd[(size_t)(b0+r)*TT + tp];
    }
  }
}

extern "C" void kernel_launch(void* const* d_in, const int* in_sizes, int n_in,
                              void* d_out, int out_size, void* d_ws, size_t ws_size,
                              hipStream_t stream) {
  (void)in_sizes; (void)n_in; (void)out_size; (void)ws_size;
  u32*  wsf = (u32*)d_ws;
  char* wsd = (char*)d_ws + 16384;
  k_init<<<dim3(16), dim3(256), 0, stream>>>(wsf);
  k_pipe<<<dim3(96), dim3(256), 0, stream>>>(
      (const float*)d_in[0],  (const float*)d_in[1],  (const float*)d_in[2],
      (const float*)d_in[3],  (const float*)d_in[4],  (const float*)d_in[5],
      (const float*)d_in[6],  (const float*)d_in[7],  (const float*)d_in[8],  (const float*)d_in[9],
      (const float*)d_in[10], (const float*)d_in[11], (const float*)d_in[12], (const float*)d_in[13],
      (const float*)d_in[14], (const float*)d_in[15], (const float*)d_in[16], (const float*)d_in[17],
      (const float*)d_in[18], (const float*)d_in[19],
      (const float*)d_in[20], (const float*)d_in[21],
      (const float*)d_in[22], (const float*)d_in[23],
      (float*)d_out, wsf, wsd);
}